// Round 1
// baseline (1000.380 us; speedup 1.0000x reference)
//
#include <hip/hip_runtime.h>

typedef __bf16 bf16;
typedef __attribute__((ext_vector_type(4))) float   f32x4;
typedef __attribute__((ext_vector_type(4))) __bf16  bf16x4;
typedef __attribute__((ext_vector_type(8))) __bf16  bf16x8;
typedef __attribute__((ext_vector_type(4))) unsigned int u32x4;

#define NB   32
#define SEQ  1024
#define HID  1024
#define HD   128

// ws element offsets (bf16 elements)
#define WT_HI  0ull
#define WT_LO  393216ull
#define Q_HI   786432ull
#define Q_LO   (Q_HI + 4194304ull)
#define K_HI   (Q_HI + 2ull*4194304ull)
#define K_LO   (Q_HI + 3ull*4194304ull)
#define VT_OFF (Q_HI + 4ull*4194304ull)

#define POFF   4194304ull            // probs offset (floats) in d_out
#define SCALE  0.08838834764831845f  // 1/sqrt(128)
#define LOG2E  1.4426950408889634f

static __device__ inline void split_f32(float x, bf16& h, bf16& l) {
    h = (bf16)x;
    l = (bf16)(x - (float)h);
}

// ---------------------------------------------------------------------------
// Kernel 0: transpose + hi/lo split of Wq/Wk/Wv -> Wt[z][n(128)][k(1024)]
// ---------------------------------------------------------------------------
__global__ __launch_bounds__(256) void prep_w(const float* __restrict__ Wq,
                                              const float* __restrict__ Wk,
                                              const float* __restrict__ Wv,
                                              bf16* __restrict__ ws) {
    int t = blockIdx.x * 256 + threadIdx.x;   // 0 .. 393215
    int z = t >> 17;                           // which matrix
    int r = t & 131071;
    int k = r >> 7;                            // 0..1023  (coalesced read)
    int n = r & 127;                           // 0..127
    const float* W = (z == 0) ? Wq : ((z == 1) ? Wk : Wv);
    float w = W[k * 128 + n];
    bf16 h, l; split_f32(w, h, l);
    size_t idx = (size_t)z * 131072 + (size_t)n * 1024 + k;
    ws[WT_HI + idx] = h;
    ws[WT_LO + idx] = l;
}

// ---------------------------------------------------------------------------
// Kernel 1: Q/K/V = X @ W + b  (bf16x2 emulated fp32 via 3 MFMAs)
// grid: 768 blocks (z = bx>>8, mtile = bx&255), 256 threads (4 waves, 2x2)
// tile 128(m) x 128(n), BK = 32
// ---------------------------------------------------------------------------
__global__ __launch_bounds__(256) void qkv_gemm(const float* __restrict__ X,
                                                const float* __restrict__ bq,
                                                const float* __restrict__ bk,
                                                const float* __restrict__ bv,
                                                bf16* __restrict__ ws) {
    __shared__ bf16 Ah[128 * 40];
    __shared__ bf16 Al[128 * 40];
    __shared__ bf16 Bh[128 * 40];
    __shared__ bf16 Bl[128 * 40];

    int z      = blockIdx.x >> 8;
    int mt_blk = blockIdx.x & 255;
    int t  = threadIdx.x;
    int w  = t >> 6;
    int l  = t & 63;
    int lm = l & 15;
    int q  = l >> 4;
    int mwb = (w & 1) * 64;
    int nwb = (w >> 1) * 64;

    const bf16* wth = ws + WT_HI + (size_t)z * 131072;
    const bf16* wtl = ws + WT_LO + (size_t)z * 131072;

    f32x4 acc[4][4] = {};

    for (int kb = 0; kb < 32; ++kb) {
        // ---- stage A: X tile 128 x 32 fp32 -> hi/lo bf16 in LDS
        for (int i = 0; i < 4; ++i) {
            int flat = i * 256 + t;
            int row  = flat >> 3;
            int k4   = (flat & 7) * 4;
            f32x4 x = *(const f32x4*)(X + (size_t)(mt_blk * 128 + row) * 1024 + kb * 32 + k4);
            bf16x4 h, lo;
            for (int j = 0; j < 4; ++j) { bf16 hh, ll; split_f32(x[j], hh, ll); h[j] = hh; lo[j] = ll; }
            *(bf16x4*)(Ah + row * 40 + k4) = h;
            *(bf16x4*)(Al + row * 40 + k4) = lo;
        }
        // ---- stage B: Wt tile 128 x 32 bf16 (hi and lo)
        for (int i = 0; i < 2; ++i) {
            int flat = i * 256 + t;
            int row  = flat >> 2;
            int k8   = (flat & 3) * 8;
            *(u32x4*)(Bh + row * 40 + k8) = *(const u32x4*)(wth + (size_t)row * 1024 + kb * 32 + k8);
            *(u32x4*)(Bl + row * 40 + k8) = *(const u32x4*)(wtl + (size_t)row * 1024 + kb * 32 + k8);
        }
        __syncthreads();

        bf16x8 ah[4], al[4], bh[4], bl[4];
        for (int mt = 0; mt < 4; ++mt) {
            int row = mwb + mt * 16 + lm;
            ah[mt] = *(const bf16x8*)(Ah + row * 40 + q * 8);
            al[mt] = *(const bf16x8*)(Al + row * 40 + q * 8);
        }
        for (int nt = 0; nt < 4; ++nt) {
            int row = nwb + nt * 16 + lm;
            bh[nt] = *(const bf16x8*)(Bh + row * 40 + q * 8);
            bl[nt] = *(const bf16x8*)(Bl + row * 40 + q * 8);
        }
        for (int mt = 0; mt < 4; ++mt)
            for (int nt = 0; nt < 4; ++nt) {
                acc[mt][nt] = __builtin_amdgcn_mfma_f32_16x16x32_bf16(ah[mt], bh[nt], acc[mt][nt], 0, 0, 0);
                acc[mt][nt] = __builtin_amdgcn_mfma_f32_16x16x32_bf16(ah[mt], bl[nt], acc[mt][nt], 0, 0, 0);
                acc[mt][nt] = __builtin_amdgcn_mfma_f32_16x16x32_bf16(al[mt], bh[nt], acc[mt][nt], 0, 0, 0);
            }
        __syncthreads();
    }

    // ---- epilogue: + bias, (Q also * 1/sqrt(D)), write hi/lo (Q,K) or Vt
    const float* bias = (z == 0) ? bq : ((z == 1) ? bk : bv);
    bf16* qh = ws + Q_HI;  bf16* ql = ws + Q_LO;
    bf16* kh = ws + K_HI;  bf16* kl = ws + K_LO;
    bf16* vt = ws + VT_OFF;
    for (int mt = 0; mt < 4; ++mt)
        for (int nt = 0; nt < 4; ++nt)
            for (int r = 0; r < 4; ++r) {
                int row = mwb + mt * 16 + q * 4 + r;
                int col = nwb + nt * 16 + lm;
                size_t grow = (size_t)mt_blk * 128 + row;
                float v = acc[mt][nt][r] + bias[col];
                if (z == 0) {
                    v *= SCALE;
                    bf16 h, lo; split_f32(v, h, lo);
                    qh[grow * 128 + col] = h;
                    ql[grow * 128 + col] = lo;
                } else if (z == 1) {
                    bf16 h, lo; split_f32(v, h, lo);
                    kh[grow * 128 + col] = h;
                    kl[grow * 128 + col] = lo;
                } else {
                    size_t b = grow >> 10;
                    size_t s = grow & 1023;
                    vt[b * 131072 + (size_t)col * 1024 + s] = (bf16)v;
                }
            }
}

// ---------------------------------------------------------------------------
// Kernel 2: scores = Q K^T (already scaled), softmax -> probs (fp32 d_out)
// grid: 512 blocks (b = bx>>4, mq = bx&15), 512 threads (8 waves)
// block computes 64 q-rows x all 1024 keys; wave w owns key cols [128w,128w+128)
// ---------------------------------------------------------------------------
__global__ __launch_bounds__(512) void scores_softmax(const bf16* __restrict__ ws,
                                                      float* __restrict__ out) {
    __shared__ bf16 Qh[64 * 136];
    __shared__ bf16 Ql[64 * 136];
    __shared__ float red[8][64];
    __shared__ float rstat[64];

    int bb = blockIdx.x >> 4;
    int mq = blockIdx.x & 15;
    int t  = threadIdx.x;
    int w  = t >> 6;
    int l  = t & 63;
    int lm = l & 15;
    int q  = l >> 4;

    const bf16* qhp = ws + Q_HI + ((size_t)bb * 1024 + mq * 64) * 128;
    const bf16* qlp = ws + Q_LO + ((size_t)bb * 1024 + mq * 64) * 128;
    for (int i = 0; i < 2; ++i) {
        int flat = i * 512 + t;
        int row  = flat >> 4;
        int k8   = (flat & 15) * 8;
        *(u32x4*)(Qh + row * 136 + k8) = *(const u32x4*)(qhp + (size_t)row * 128 + k8);
        *(u32x4*)(Ql + row * 136 + k8) = *(const u32x4*)(qlp + (size_t)row * 128 + k8);
    }
    __syncthreads();

    const bf16* khp = ws + K_HI + (size_t)bb * 1024 * 128;
    const bf16* klp = ws + K_LO + (size_t)bb * 1024 * 128;

    f32x4 acc[4][8] = {};
    for (int kc = 0; kc < 4; ++kc) {
        bf16x8 ah[4], al[4];
        for (int mt = 0; mt < 4; ++mt) {
            int row = mt * 16 + lm;
            ah[mt] = *(const bf16x8*)(Qh + row * 136 + kc * 32 + q * 8);
            al[mt] = *(const bf16x8*)(Ql + row * 136 + kc * 32 + q * 8);
        }
        for (int nt = 0; nt < 8; ++nt) {
            size_t key = (size_t)w * 128 + nt * 16 + lm;
            bf16x8 bh = *(const bf16x8*)(khp + key * 128 + kc * 32 + q * 8);
            bf16x8 bl = *(const bf16x8*)(klp + key * 128 + kc * 32 + q * 8);
            for (int mt = 0; mt < 4; ++mt) {
                acc[mt][nt] = __builtin_amdgcn_mfma_f32_16x16x32_bf16(ah[mt], bh, acc[mt][nt], 0, 0, 0);
                acc[mt][nt] = __builtin_amdgcn_mfma_f32_16x16x32_bf16(ah[mt], bl, acc[mt][nt], 0, 0, 0);
                acc[mt][nt] = __builtin_amdgcn_mfma_f32_16x16x32_bf16(al[mt], bh, acc[mt][nt], 0, 0, 0);
            }
        }
    }

    // ---- row max (per-lane over nt, quad shuffle over lm, LDS over waves)
    for (int mt = 0; mt < 4; ++mt)
        for (int r = 0; r < 4; ++r) {
            float m = acc[mt][0][r];
            for (int nt = 1; nt < 8; ++nt) m = fmaxf(m, acc[mt][nt][r]);
            m = fmaxf(m, __shfl_xor(m, 1));
            m = fmaxf(m, __shfl_xor(m, 2));
            m = fmaxf(m, __shfl_xor(m, 4));
            m = fmaxf(m, __shfl_xor(m, 8));
            if (lm == 0) red[w][mt * 16 + q * 4 + r] = m;
        }
    __syncthreads();
    if (t < 64) {
        float m = red[0][t];
        for (int ww = 1; ww < 8; ++ww) m = fmaxf(m, red[ww][t]);
        rstat[t] = m;
    }
    __syncthreads();

    // ---- exp + row sum
    for (int mt = 0; mt < 4; ++mt)
        for (int r = 0; r < 4; ++r) {
            float rm = rstat[mt * 16 + q * 4 + r];
            float s = 0.f;
            for (int nt = 0; nt < 8; ++nt) {
                float e = exp2f((acc[mt][nt][r] - rm) * LOG2E);
                acc[mt][nt][r] = e;
                s += e;
            }
            s += __shfl_xor(s, 1);
            s += __shfl_xor(s, 2);
            s += __shfl_xor(s, 4);
            s += __shfl_xor(s, 8);
            if (lm == 0) red[w][mt * 16 + q * 4 + r] = s;
        }
    __syncthreads();
    if (t < 64) {
        float s = 0.f;
        for (int ww = 0; ww < 8; ++ww) s += red[ww][t];
        rstat[t] = 1.0f / s;
    }
    __syncthreads();

    // ---- normalize + store probs fp32
    float* pout = out + POFF + (size_t)bb * 1048576;
    for (int mt = 0; mt < 4; ++mt)
        for (int r = 0; r < 4; ++r) {
            float inv = rstat[mt * 16 + q * 4 + r];
            int row = mq * 64 + mt * 16 + q * 4 + r;
            for (int nt = 0; nt < 8; ++nt) {
                int col = w * 128 + nt * 16 + lm;
                pout[(size_t)row * 1024 + col] = acc[mt][nt][r] * inv;
            }
        }
}

// ---------------------------------------------------------------------------
// Kernel 3: out = probs @ V   (single bf16 MFMA)
// grid: 256 blocks (128 q-rows each), 256 threads (4 waves 2x2), BK = 64
// ---------------------------------------------------------------------------
__global__ __launch_bounds__(256) void pv_gemm(const float* __restrict__ probs,
                                               const bf16* __restrict__ ws,
                                               float* __restrict__ outp) {
    __shared__ bf16 As[128 * 72];
    __shared__ bf16 Bs[128 * 72];

    int blk = blockIdx.x;
    int bb  = blk >> 3;
    int sb  = (blk & 7) * 128;
    int t  = threadIdx.x;
    int w  = t >> 6;
    int l  = t & 63;
    int lm = l & 15;
    int q  = l >> 4;
    int mwb = (w & 1) * 64;
    int nwb = (w >> 1) * 64;

    const float* P = probs + (size_t)bb * 1048576 + (size_t)sb * 1024;
    const bf16*  V = ws + VT_OFF + (size_t)bb * 131072;

    f32x4 acc[4][4] = {};
    for (int kb = 0; kb < 16; ++kb) {
        // stage A: probs 128 x 64 fp32 -> bf16
        for (int i = 0; i < 8; ++i) {
            int flat = i * 256 + t;
            int row  = flat >> 4;
            int k4   = (flat & 15) * 4;
            f32x4 x = *(const f32x4*)(P + (size_t)row * 1024 + kb * 64 + k4);
            bf16x4 h;
            for (int j = 0; j < 4; ++j) h[j] = (bf16)x[j];
            *(bf16x4*)(As + row * 72 + k4) = h;
        }
        // stage B: Vt 128(d) x 64(s) bf16
        for (int i = 0; i < 4; ++i) {
            int flat = i * 256 + t;
            int row  = flat >> 3;
            int k8   = (flat & 7) * 8;
            *(u32x4*)(Bs + row * 72 + k8) = *(const u32x4*)(V + (size_t)row * 1024 + kb * 64 + k8);
        }
        __syncthreads();
        for (int kc = 0; kc < 2; ++kc) {
            bf16x8 a[4], b[4];
            for (int mt = 0; mt < 4; ++mt)
                a[mt] = *(const bf16x8*)(As + (mwb + mt * 16 + lm) * 72 + kc * 32 + q * 8);
            for (int nt = 0; nt < 4; ++nt)
                b[nt] = *(const bf16x8*)(Bs + (nwb + nt * 16 + lm) * 72 + kc * 32 + q * 8);
            for (int mt = 0; mt < 4; ++mt)
                for (int nt = 0; nt < 4; ++nt)
                    acc[mt][nt] = __builtin_amdgcn_mfma_f32_16x16x32_bf16(a[mt], b[nt], acc[mt][nt], 0, 0, 0);
        }
        __syncthreads();
    }

    for (int mt = 0; mt < 4; ++mt)
        for (int nt = 0; nt < 4; ++nt)
            for (int r = 0; r < 4; ++r) {
                int row = mwb + mt * 16 + q * 4 + r;
                int col = nwb + nt * 16 + lm;
                outp[((size_t)bb * 1024 + sb + row) * 128 + col] = acc[mt][nt][r];
            }
}

// ---------------------------------------------------------------------------
extern "C" void kernel_launch(void* const* d_in, const int* in_sizes, int n_in,
                              void* d_out, int out_size, void* d_ws, size_t ws_size,
                              hipStream_t stream) {
    const float* X  = (const float*)d_in[0];
    const float* Wq = (const float*)d_in[1];
    const float* bq = (const float*)d_in[2];
    const float* Wk = (const float*)d_in[3];
    const float* bk = (const float*)d_in[4];
    const float* Wv = (const float*)d_in[5];
    const float* bv = (const float*)d_in[6];
    float* out = (float*)d_out;
    bf16* ws   = (bf16*)d_ws;

    prep_w<<<1536, 256, 0, stream>>>(Wq, Wk, Wv, ws);
    qkv_gemm<<<768, 256, 0, stream>>>(X, bq, bk, bv, ws);
    scores_softmax<<<512, 512, 0, stream>>>(ws, out);
    pv_gemm<<<256, 256, 0, stream>>>(out + POFF, ws, out);
}

// Round 2
// 466.473 us; speedup vs baseline: 2.1446x; 2.1446x over previous
//
#include <hip/hip_runtime.h>

typedef __bf16 bf16;
typedef __attribute__((ext_vector_type(4))) float   f32x4;
typedef __attribute__((ext_vector_type(4))) __bf16  bf16x4;
typedef __attribute__((ext_vector_type(8))) __bf16  bf16x8;
typedef __attribute__((ext_vector_type(4))) unsigned int u32x4;

#define NB   32
#define SEQ  1024
#define HID  1024
#define HD   128

// ws element offsets (bf16 elements)
#define WT_HI  0ull
#define WT_LO  393216ull
#define Q_HI   786432ull
#define Q_LO   (Q_HI + 4194304ull)
#define K_HI   (Q_HI + 2ull*4194304ull)
#define K_LO   (Q_HI + 3ull*4194304ull)
#define VT_OFF (Q_HI + 4ull*4194304ull)

#define POFF   4194304ull            // probs offset (floats) in d_out
#define SCALE  0.08838834764831845f  // 1/sqrt(128)
#define LOG2E  1.4426950408889634f

#define GLL16(g, l)                                                         \
    __builtin_amdgcn_global_load_lds(                                        \
        (const __attribute__((address_space(1))) void*)(g),                  \
        (__attribute__((address_space(3))) void*)(l), 16, 0, 0)

static __device__ inline void split_f32(float x, bf16& h, bf16& l) {
    h = (bf16)x;
    l = (bf16)(x - (float)h);
}

// ---------------------------------------------------------------------------
// Kernel A: split X fp32 -> Xh/Xl bf16 (stored in probs region of d_out)
// ---------------------------------------------------------------------------
__global__ __launch_bounds__(256) void prep_x(const float* __restrict__ X,
                                              bf16* __restrict__ Xh,
                                              bf16* __restrict__ Xl) {
    size_t t = (size_t)blockIdx.x * 256 + threadIdx.x;  // * 8 elements
    f32x4 a = *(const f32x4*)(X + t * 8);
    f32x4 b = *(const f32x4*)(X + t * 8 + 4);
    bf16x8 h, lo;
    for (int j = 0; j < 4; ++j) {
        bf16 hh, ll;
        split_f32(a[j], hh, ll); h[j] = hh;     lo[j] = ll;
        split_f32(b[j], hh, ll); h[4 + j] = hh; lo[4 + j] = ll;
    }
    *(bf16x8*)(Xh + t * 8) = h;
    *(bf16x8*)(Xl + t * 8) = lo;
}

// ---------------------------------------------------------------------------
// Kernel 0: transpose + hi/lo split of Wq/Wk/Wv -> Wt[z][n(128)][k(1024)]
// ---------------------------------------------------------------------------
__global__ __launch_bounds__(256) void prep_w(const float* __restrict__ Wq,
                                              const float* __restrict__ Wk,
                                              const float* __restrict__ Wv,
                                              bf16* __restrict__ ws) {
    int t = blockIdx.x * 256 + threadIdx.x;   // 0 .. 393215
    int z = t >> 17;                           // which matrix
    int r = t & 131071;
    int k = r >> 7;                            // 0..1023  (coalesced read)
    int n = r & 127;                           // 0..127
    const float* W = (z == 0) ? Wq : ((z == 1) ? Wk : Wv);
    float w = W[k * 128 + n];
    bf16 h, l; split_f32(w, h, l);
    size_t idx = (size_t)z * 131072 + (size_t)n * 1024 + k;
    ws[WT_HI + idx] = h;
    ws[WT_LO + idx] = l;
}

// ---------------------------------------------------------------------------
// Kernel 1: Q/K/V = X @ W + b  (bf16x2 emulated fp32 via 3 MFMAs)
// grid: 768 blocks (z = bx>>8, mtile = bx&255), 256 threads (4 waves, 2x2)
// tile 128(m) x 128(n), BK = 32, global_load_lds staging, unpadded LDS
// ---------------------------------------------------------------------------
__global__ __launch_bounds__(256) void qkv_gemm(const bf16* __restrict__ Xh,
                                                const bf16* __restrict__ Xl,
                                                const float* __restrict__ bq,
                                                const float* __restrict__ bk,
                                                const float* __restrict__ bv,
                                                bf16* __restrict__ ws) {
    __shared__ __align__(16) bf16 smem[17408];   // 34816 B; tiles + epilogue buf
    bf16* Ah = smem;
    bf16* Al = smem + 4096;
    bf16* Bh = smem + 8192;
    bf16* Bl = smem + 12288;

    int z      = blockIdx.x >> 8;
    int mt_blk = blockIdx.x & 255;
    int t  = threadIdx.x;
    int w  = t >> 6;
    int l  = t & 63;
    int lm = l & 15;
    int q  = l >> 4;
    int mwb = (w & 1) * 64;
    int nwb = (w >> 1) * 64;

    const bf16* wth = ws + WT_HI + (size_t)z * 131072;
    const bf16* wtl = ws + WT_LO + (size_t)z * 131072;

    // staging: wave w loads rows [w*32, w*32+32) of each 128x32 tile.
    // lane i covers row += (i>>2), col (i&3)*8; LDS dest = uniform base + i*16B
    int srow = w * 32 + (l >> 2);
    int scol = (l & 3) * 8;
    const bf16* gAh = Xh + (size_t)(mt_blk * 128 + srow) * 1024 + scol;
    const bf16* gAl = Xl + (size_t)(mt_blk * 128 + srow) * 1024 + scol;
    const bf16* gBh = wth + (size_t)srow * 1024 + scol;
    const bf16* gBl = wtl + (size_t)srow * 1024 + scol;
    int lbase0 = (w * 32) * 32;       // elements
    int lbase1 = (w * 32 + 16) * 32;

    f32x4 acc[4][4] = {};

    for (int kb = 0; kb < 32; ++kb) {
        int go = kb * 32;
        GLL16(gAh + go,           Ah + lbase0);
        GLL16(gAh + go + 16384,   Ah + lbase1);   // +16 rows * 1024
        GLL16(gAl + go,           Al + lbase0);
        GLL16(gAl + go + 16384,   Al + lbase1);
        GLL16(gBh + go,           Bh + lbase0);
        GLL16(gBh + go + 16384,   Bh + lbase1);
        GLL16(gBl + go,           Bl + lbase0);
        GLL16(gBl + go + 16384,   Bl + lbase1);
        __syncthreads();

        bf16x8 ah[4], al[4], bh[4], bl[4];
        for (int mt = 0; mt < 4; ++mt) {
            int row = mwb + mt * 16 + lm;
            ah[mt] = *(const bf16x8*)(Ah + row * 32 + q * 8);
            al[mt] = *(const bf16x8*)(Al + row * 32 + q * 8);
        }
        for (int nt = 0; nt < 4; ++nt) {
            int row = nwb + nt * 16 + lm;
            bh[nt] = *(const bf16x8*)(Bh + row * 32 + q * 8);
            bl[nt] = *(const bf16x8*)(Bl + row * 32 + q * 8);
        }
        for (int mt = 0; mt < 4; ++mt)
            for (int nt = 0; nt < 4; ++nt) {
                acc[mt][nt] = __builtin_amdgcn_mfma_f32_16x16x32_bf16(ah[mt], bh[nt], acc[mt][nt], 0, 0, 0);
                acc[mt][nt] = __builtin_amdgcn_mfma_f32_16x16x32_bf16(ah[mt], bl[nt], acc[mt][nt], 0, 0, 0);
                acc[mt][nt] = __builtin_amdgcn_mfma_f32_16x16x32_bf16(al[mt], bh[nt], acc[mt][nt], 0, 0, 0);
            }
        __syncthreads();
    }

    // ---- epilogue via LDS: fully-coalesced 16B stores
    const float* bias = (z == 0) ? bq : ((z == 1) ? bk : bv);
    float scale = (z == 0) ? SCALE : 1.0f;

    if (z < 2) {
        bf16* dh = ws + ((z == 0) ? Q_HI : K_HI);
        bf16* dl = ws + ((z == 0) ? Q_LO : K_LO);
        // pass 1: hi
        for (int mt = 0; mt < 4; ++mt)
            for (int nt = 0; nt < 4; ++nt)
                for (int r = 0; r < 4; ++r) {
                    int row = mwb + mt * 16 + q * 4 + r;
                    int col = nwb + nt * 16 + lm;
                    float v = (acc[mt][nt][r] + bias[col]) * scale;
                    smem[row * 136 + col] = (bf16)v;
                }
        __syncthreads();
        for (int i = 0; i < 8; ++i) {
            int idx = i * 2048 + t * 8;
            int row = idx >> 7, col = idx & 127;
            bf16x8 vv = *(const bf16x8*)(smem + row * 136 + col);
            *(bf16x8*)(dh + ((size_t)(mt_blk * 128 + row)) * 128 + col) = vv;
        }
        __syncthreads();
        // pass 2: lo
        for (int mt = 0; mt < 4; ++mt)
            for (int nt = 0; nt < 4; ++nt)
                for (int r = 0; r < 4; ++r) {
                    int row = mwb + mt * 16 + q * 4 + r;
                    int col = nwb + nt * 16 + lm;
                    float v = (acc[mt][nt][r] + bias[col]) * scale;
                    bf16 h = (bf16)v;
                    smem[row * 136 + col] = (bf16)(v - (float)h);
                }
        __syncthreads();
        for (int i = 0; i < 8; ++i) {
            int idx = i * 2048 + t * 8;
            int row = idx >> 7, col = idx & 127;
            bf16x8 vv = *(const bf16x8*)(smem + row * 136 + col);
            *(bf16x8*)(dl + ((size_t)(mt_blk * 128 + row)) * 128 + col) = vv;
        }
    } else {
        // Vt: transpose in LDS so stores are contiguous along s
        bf16* vt = ws + VT_OFF;
        size_t b  = mt_blk >> 3;
        int   sb  = (mt_blk & 7) * 128;
        for (int mt = 0; mt < 4; ++mt)
            for (int nt = 0; nt < 4; ++nt)
                for (int r = 0; r < 4; ++r) {
                    int row = mwb + mt * 16 + q * 4 + r;   // s within tile
                    int col = nwb + nt * 16 + lm;          // d
                    float v = acc[mt][nt][r] + bias[col];
                    smem[col * 136 + row] = (bf16)v;
                }
        __syncthreads();
        for (int i = 0; i < 8; ++i) {
            int idx = i * 2048 + t * 8;
            int d = idx >> 7, s8 = idx & 127;
            bf16x8 vv = *(const bf16x8*)(smem + d * 136 + s8);
            *(bf16x8*)(vt + b * 131072 + (size_t)d * 1024 + sb + s8) = vv;
        }
    }
}

// ---------------------------------------------------------------------------
// Kernel 2: scores = Q K^T (already scaled), softmax -> probs (fp32 d_out)
// grid: 512 blocks (b = bx>>4, mq = bx&15), 512 threads (8 waves)
// block computes 64 q-rows x all 1024 keys; wave w owns key cols [128w,128w+128)
// ---------------------------------------------------------------------------
__global__ __launch_bounds__(512) void scores_softmax(const bf16* __restrict__ ws,
                                                      float* __restrict__ out) {
    __shared__ bf16 Qh[64 * 136];
    __shared__ bf16 Ql[64 * 136];
    __shared__ float red[8][64];
    __shared__ float rstat[64];

    int bb = blockIdx.x >> 4;
    int mq = blockIdx.x & 15;
    int t  = threadIdx.x;
    int w  = t >> 6;
    int l  = t & 63;
    int lm = l & 15;
    int q  = l >> 4;

    const bf16* qhp = ws + Q_HI + ((size_t)bb * 1024 + mq * 64) * 128;
    const bf16* qlp = ws + Q_LO + ((size_t)bb * 1024 + mq * 64) * 128;
    for (int i = 0; i < 2; ++i) {
        int flat = i * 512 + t;
        int row  = flat >> 4;
        int k8   = (flat & 15) * 8;
        *(u32x4*)(Qh + row * 136 + k8) = *(const u32x4*)(qhp + (size_t)row * 128 + k8);
        *(u32x4*)(Ql + row * 136 + k8) = *(const u32x4*)(qlp + (size_t)row * 128 + k8);
    }
    __syncthreads();

    const bf16* khp = ws + K_HI + (size_t)bb * 1024 * 128;
    const bf16* klp = ws + K_LO + (size_t)bb * 1024 * 128;

    f32x4 acc[4][8] = {};
    for (int kc = 0; kc < 4; ++kc) {
        bf16x8 ah[4], al[4];
        for (int mt = 0; mt < 4; ++mt) {
            int row = mt * 16 + lm;
            ah[mt] = *(const bf16x8*)(Qh + row * 136 + kc * 32 + q * 8);
            al[mt] = *(const bf16x8*)(Ql + row * 136 + kc * 32 + q * 8);
        }
        for (int nt = 0; nt < 8; ++nt) {
            size_t key = (size_t)w * 128 + nt * 16 + lm;
            bf16x8 bh = *(const bf16x8*)(khp + key * 128 + kc * 32 + q * 8);
            bf16x8 bl = *(const bf16x8*)(klp + key * 128 + kc * 32 + q * 8);
            for (int mt = 0; mt < 4; ++mt) {
                acc[mt][nt] = __builtin_amdgcn_mfma_f32_16x16x32_bf16(ah[mt], bh, acc[mt][nt], 0, 0, 0);
                acc[mt][nt] = __builtin_amdgcn_mfma_f32_16x16x32_bf16(ah[mt], bl, acc[mt][nt], 0, 0, 0);
                acc[mt][nt] = __builtin_amdgcn_mfma_f32_16x16x32_bf16(al[mt], bh, acc[mt][nt], 0, 0, 0);
            }
        }
    }

    // ---- row max (per-lane over nt, quad shuffle over lm, LDS over waves)
    for (int mt = 0; mt < 4; ++mt)
        for (int r = 0; r < 4; ++r) {
            float m = acc[mt][0][r];
            for (int nt = 1; nt < 8; ++nt) m = fmaxf(m, acc[mt][nt][r]);
            m = fmaxf(m, __shfl_xor(m, 1));
            m = fmaxf(m, __shfl_xor(m, 2));
            m = fmaxf(m, __shfl_xor(m, 4));
            m = fmaxf(m, __shfl_xor(m, 8));
            if (lm == 0) red[w][mt * 16 + q * 4 + r] = m;
        }
    __syncthreads();
    if (t < 64) {
        float m = red[0][t];
        for (int ww = 1; ww < 8; ++ww) m = fmaxf(m, red[ww][t]);
        rstat[t] = m;
    }
    __syncthreads();

    // ---- exp + row sum
    for (int mt = 0; mt < 4; ++mt)
        for (int r = 0; r < 4; ++r) {
            float rm = rstat[mt * 16 + q * 4 + r];
            float s = 0.f;
            for (int nt = 0; nt < 8; ++nt) {
                float e = exp2f((acc[mt][nt][r] - rm) * LOG2E);
                acc[mt][nt][r] = e;
                s += e;
            }
            s += __shfl_xor(s, 1);
            s += __shfl_xor(s, 2);
            s += __shfl_xor(s, 4);
            s += __shfl_xor(s, 8);
            if (lm == 0) red[w][mt * 16 + q * 4 + r] = s;
        }
    __syncthreads();
    if (t < 64) {
        float s = 0.f;
        for (int ww = 0; ww < 8; ++ww) s += red[ww][t];
        rstat[t] = 1.0f / s;
    }
    __syncthreads();

    // ---- normalize + store probs fp32
    float* pout = out + POFF + (size_t)bb * 1048576;
    for (int mt = 0; mt < 4; ++mt)
        for (int r = 0; r < 4; ++r) {
            float inv = rstat[mt * 16 + q * 4 + r];
            int row = mq * 64 + mt * 16 + q * 4 + r;
            for (int nt = 0; nt < 8; ++nt) {
                int col = w * 128 + nt * 16 + lm;
                pout[(size_t)row * 1024 + col] = acc[mt][nt][r] * inv;
            }
        }
}

// ---------------------------------------------------------------------------
// Kernel 3: out = probs @ V   (single bf16 MFMA)
// grid: 256 blocks (128 q-rows each), 256 threads (4 waves 2x2), BK = 64
// ---------------------------------------------------------------------------
__global__ __launch_bounds__(256) void pv_gemm(const float* __restrict__ probs,
                                               const bf16* __restrict__ ws,
                                               float* __restrict__ outp) {
    __shared__ bf16 As[128 * 72];
    __shared__ bf16 Bs[128 * 72];

    int blk = blockIdx.x;
    int bb  = blk >> 3;
    int sb  = (blk & 7) * 128;
    int t  = threadIdx.x;
    int w  = t >> 6;
    int l  = t & 63;
    int lm = l & 15;
    int q  = l >> 4;
    int mwb = (w & 1) * 64;
    int nwb = (w >> 1) * 64;

    const float* P = probs + (size_t)bb * 1048576 + (size_t)sb * 1024;
    const bf16*  V = ws + VT_OFF + (size_t)bb * 131072;

    f32x4 acc[4][4] = {};
    for (int kb = 0; kb < 16; ++kb) {
        // stage A: probs 128 x 64 fp32 -> bf16
        for (int i = 0; i < 8; ++i) {
            int flat = i * 256 + t;
            int row  = flat >> 4;
            int k4   = (flat & 15) * 4;
            f32x4 x = *(const f32x4*)(P + (size_t)row * 1024 + kb * 64 + k4);
            bf16x4 h;
            for (int j = 0; j < 4; ++j) h[j] = (bf16)x[j];
            *(bf16x4*)(As + row * 72 + k4) = h;
        }
        // stage B: Vt 128(d) x 64(s) bf16
        for (int i = 0; i < 4; ++i) {
            int flat = i * 256 + t;
            int row  = flat >> 3;
            int k8   = (flat & 7) * 8;
            *(u32x4*)(Bs + row * 72 + k8) = *(const u32x4*)(V + (size_t)row * 1024 + kb * 64 + k8);
        }
        __syncthreads();
        for (int kc = 0; kc < 2; ++kc) {
            bf16x8 a[4], b[4];
            for (int mt = 0; mt < 4; ++mt)
                a[mt] = *(const bf16x8*)(As + (mwb + mt * 16 + lm) * 72 + kc * 32 + q * 8);
            for (int nt = 0; nt < 4; ++nt)
                b[nt] = *(const bf16x8*)(Bs + (nwb + nt * 16 + lm) * 72 + kc * 32 + q * 8);
            for (int mt = 0; mt < 4; ++mt)
                for (int nt = 0; nt < 4; ++nt)
                    acc[mt][nt] = __builtin_amdgcn_mfma_f32_16x16x32_bf16(a[mt], b[nt], acc[mt][nt], 0, 0, 0);
        }
        __syncthreads();
    }

    for (int mt = 0; mt < 4; ++mt)
        for (int nt = 0; nt < 4; ++nt)
            for (int r = 0; r < 4; ++r) {
                int row = mwb + mt * 16 + q * 4 + r;
                int col = nwb + nt * 16 + lm;
                outp[((size_t)bb * 1024 + sb + row) * 128 + col] = acc[mt][nt][r];
            }
}

// ---------------------------------------------------------------------------
extern "C" void kernel_launch(void* const* d_in, const int* in_sizes, int n_in,
                              void* d_out, int out_size, void* d_ws, size_t ws_size,
                              hipStream_t stream) {
    const float* X  = (const float*)d_in[0];
    const float* Wq = (const float*)d_in[1];
    const float* bq = (const float*)d_in[2];
    const float* Wk = (const float*)d_in[3];
    const float* bk = (const float*)d_in[4];
    const float* Wv = (const float*)d_in[5];
    const float* bv = (const float*)d_in[6];
    float* out = (float*)d_out;
    bf16* ws   = (bf16*)d_ws;

    // Xh/Xl live in the (not-yet-needed) probs region of d_out: 2 * 67 MB = 134 MB
    bf16* Xh = (bf16*)(out + POFF);
    bf16* Xl = Xh + 33554432ull;

    prep_x<<<16384, 256, 0, stream>>>(X, Xh, Xl);
    prep_w<<<1536, 256, 0, stream>>>(Wq, Wk, Wv, ws);
    qkv_gemm<<<768, 256, 0, stream>>>(Xh, Xl, bq, bk, bv, ws);
    scores_softmax<<<512, 512, 0, stream>>>(ws, out);
    pv_gemm<<<256, 256, 0, stream>>>(out + POFF, ws, out);
}

// Round 3
// 449.271 us; speedup vs baseline: 2.2267x; 1.0383x over previous
//
#include <hip/hip_runtime.h>

typedef __bf16 bf16;
typedef __attribute__((ext_vector_type(4))) float   f32x4;
typedef __attribute__((ext_vector_type(4))) __bf16  bf16x4;
typedef __attribute__((ext_vector_type(8))) __bf16  bf16x8;
typedef __attribute__((ext_vector_type(4))) unsigned int u32x4;

#define NB   32
#define SEQ  1024
#define HID  1024
#define HD   128

// ws element offsets (bf16 elements)
#define WT_HI  0ull
#define WT_LO  393216ull
#define Q_HI   786432ull
#define Q_LO   (Q_HI + 4194304ull)
#define K_HI   (Q_HI + 2ull*4194304ull)
#define K_LO   (Q_HI + 3ull*4194304ull)
#define VT_OFF (Q_HI + 4ull*4194304ull)

#define POFF   4194304ull            // probs offset (floats) in d_out
#define SCALE  0.08838834764831845f  // 1/sqrt(128)
#define LOG2E  1.4426950408889634f

#define GLL16(g, l)                                                         \
    __builtin_amdgcn_global_load_lds(                                        \
        (const __attribute__((address_space(1))) void*)(g),                  \
        (__attribute__((address_space(3))) void*)(l), 16, 0, 0)

static __device__ inline void split_f32(float x, bf16& h, bf16& l) {
    h = (bf16)x;
    l = (bf16)(x - (float)h);
}

// ---------------------------------------------------------------------------
// Kernel A: split X fp32 -> Xh/Xl bf16 (stored in probs region of d_out)
// ---------------------------------------------------------------------------
__global__ __launch_bounds__(256) void prep_x(const float* __restrict__ X,
                                              bf16* __restrict__ Xh,
                                              bf16* __restrict__ Xl) {
    size_t t = (size_t)blockIdx.x * 256 + threadIdx.x;  // * 8 elements
    f32x4 a = *(const f32x4*)(X + t * 8);
    f32x4 b = *(const f32x4*)(X + t * 8 + 4);
    bf16x8 h, lo;
    for (int j = 0; j < 4; ++j) {
        bf16 hh, ll;
        split_f32(a[j], hh, ll); h[j] = hh;     lo[j] = ll;
        split_f32(b[j], hh, ll); h[4 + j] = hh; lo[4 + j] = ll;
    }
    *(bf16x8*)(Xh + t * 8) = h;
    *(bf16x8*)(Xl + t * 8) = lo;
}

// ---------------------------------------------------------------------------
// Kernel 0: transpose + hi/lo split of Wq/Wk/Wv -> Wt[z][n(128)][k(1024)]
// grid: 48 blocks = z(3) x ktile(16, 64 rows each); LDS transpose, all
// global reads/writes coalesced 16B.
// ---------------------------------------------------------------------------
__global__ __launch_bounds__(256) void prep_w(const float* __restrict__ Wq,
                                              const float* __restrict__ Wk,
                                              const float* __restrict__ Wv,
                                              bf16* __restrict__ ws) {
    __shared__ bf16 Th[128 * 72];
    __shared__ bf16 Tl[128 * 72];
    int z  = blockIdx.x >> 4;
    int kt = blockIdx.x & 15;
    const float* W = (z == 0) ? Wq : ((z == 1) ? Wk : Wv);
    int t = threadIdx.x;

    // read 64 rows (k) x 128 cols (n), split, scatter into LDS transposed
    for (int i = 0; i < 8; ++i) {
        int idx = (i * 256 + t) * 4;
        int kl  = idx >> 7;          // 0..63
        int n   = idx & 127;
        f32x4 v = *(const f32x4*)(W + (size_t)(kt * 64 + kl) * 128 + n);
        for (int j = 0; j < 4; ++j) {
            bf16 h, lo; split_f32(v[j], h, lo);
            Th[(n + j) * 72 + kl] = h;
            Tl[(n + j) * 72 + kl] = lo;
        }
    }
    __syncthreads();
    // write [n][k] coalesced
    for (int i = 0; i < 4; ++i) {
        int idx = (i * 256 + t) * 8;
        int n   = idx >> 6;
        int kl  = idx & 63;
        bf16x8 vh = *(const bf16x8*)(Th + n * 72 + kl);
        bf16x8 vl = *(const bf16x8*)(Tl + n * 72 + kl);
        size_t o = (size_t)z * 131072 + (size_t)n * 1024 + kt * 64 + kl;
        *(bf16x8*)(ws + WT_HI + o) = vh;
        *(bf16x8*)(ws + WT_LO + o) = vl;
    }
}

// ---------------------------------------------------------------------------
// Kernel 1: Q/K/V = X @ W + b  (bf16x2 emulated fp32 via 3 MFMAs)
// grid: 768 blocks (z = bx>>8, mtile = bx&255), 256 threads (4 waves, 2x2)
// tile 128(m) x 128(n), BK = 32, global_load_lds staging, XOR-swizzled LDS
// ---------------------------------------------------------------------------
__global__ __launch_bounds__(256) void qkv_gemm(const bf16* __restrict__ Xh,
                                                const bf16* __restrict__ Xl,
                                                const float* __restrict__ bq,
                                                const float* __restrict__ bk,
                                                const float* __restrict__ bv,
                                                bf16* __restrict__ ws) {
    __shared__ __align__(16) bf16 smem[17408];   // 34816 B; tiles + epilogue buf
    bf16* Ah = smem;
    bf16* Al = smem + 4096;
    bf16* Bh = smem + 8192;
    bf16* Bl = smem + 12288;

    int z      = blockIdx.x >> 8;
    int mt_blk = blockIdx.x & 255;
    int t  = threadIdx.x;
    int w  = t >> 6;
    int l  = t & 63;
    int lm = l & 15;
    int q  = l >> 4;
    int mwb = (w & 1) * 64;
    int nwb = (w >> 1) * 64;

    const bf16* wth = ws + WT_HI + (size_t)z * 131072;
    const bf16* wtl = ws + WT_LO + (size_t)z * 131072;

    // staging: wave w loads rows [w*32, w*32+32) of each 128x32 tile.
    // XOR swizzle: LDS slot (r, cb) holds global (r, cb ^ ((r>>1)&3));
    // for lane i: r = w*32+(i>>2), slot cb = i&3 -> global cb = (i&3)^((i>>3)&3)
    int srow = w * 32 + (l >> 2);
    int scol = ((l & 3) ^ ((l >> 3) & 3)) * 8;
    const bf16* gAh = Xh + (size_t)(mt_blk * 128 + srow) * 1024 + scol;
    const bf16* gAl = Xl + (size_t)(mt_blk * 128 + srow) * 1024 + scol;
    const bf16* gBh = wth + (size_t)srow * 1024 + scol;
    const bf16* gBl = wtl + (size_t)srow * 1024 + scol;
    int lbase0 = (w * 32) * 32;       // elements
    int lbase1 = (w * 32 + 16) * 32;

    // fragment-read swizzle: row = base16k + lm -> sw = (lm>>1)&3 (const/lane)
    int fcol = (q ^ ((lm >> 1) & 3)) * 8;

    f32x4 acc[4][4] = {};

    for (int kb = 0; kb < 32; ++kb) {
        int go = kb * 32;
        GLL16(gAh + go,           Ah + lbase0);
        GLL16(gAh + go + 16384,   Ah + lbase1);   // +16 rows * 1024
        GLL16(gAl + go,           Al + lbase0);
        GLL16(gAl + go + 16384,   Al + lbase1);
        GLL16(gBh + go,           Bh + lbase0);
        GLL16(gBh + go + 16384,   Bh + lbase1);
        GLL16(gBl + go,           Bl + lbase0);
        GLL16(gBl + go + 16384,   Bl + lbase1);
        __syncthreads();

        bf16x8 ah[4], al[4], bh[4], bl[4];
        for (int mt = 0; mt < 4; ++mt) {
            int row = mwb + mt * 16 + lm;
            ah[mt] = *(const bf16x8*)(Ah + row * 32 + fcol);
            al[mt] = *(const bf16x8*)(Al + row * 32 + fcol);
        }
        for (int nt = 0; nt < 4; ++nt) {
            int row = nwb + nt * 16 + lm;
            bh[nt] = *(const bf16x8*)(Bh + row * 32 + fcol);
            bl[nt] = *(const bf16x8*)(Bl + row * 32 + fcol);
        }
        for (int mt = 0; mt < 4; ++mt)
            for (int nt = 0; nt < 4; ++nt) {
                acc[mt][nt] = __builtin_amdgcn_mfma_f32_16x16x32_bf16(ah[mt], bh[nt], acc[mt][nt], 0, 0, 0);
                acc[mt][nt] = __builtin_amdgcn_mfma_f32_16x16x32_bf16(ah[mt], bl[nt], acc[mt][nt], 0, 0, 0);
                acc[mt][nt] = __builtin_amdgcn_mfma_f32_16x16x32_bf16(al[mt], bh[nt], acc[mt][nt], 0, 0, 0);
            }
        __syncthreads();
    }

    // ---- epilogue via LDS: fully-coalesced 16B stores
    const float* bias = (z == 0) ? bq : ((z == 1) ? bk : bv);
    float scale = (z == 0) ? SCALE : 1.0f;

    if (z < 2) {
        bf16* dh = ws + ((z == 0) ? Q_HI : K_HI);
        bf16* dl = ws + ((z == 0) ? Q_LO : K_LO);
        // pass 1: hi
        for (int mt = 0; mt < 4; ++mt)
            for (int nt = 0; nt < 4; ++nt)
                for (int r = 0; r < 4; ++r) {
                    int row = mwb + mt * 16 + q * 4 + r;
                    int col = nwb + nt * 16 + lm;
                    float v = (acc[mt][nt][r] + bias[col]) * scale;
                    smem[row * 136 + col] = (bf16)v;
                }
        __syncthreads();
        for (int i = 0; i < 8; ++i) {
            int idx = i * 2048 + t * 8;
            int row = idx >> 7, col = idx & 127;
            bf16x8 vv = *(const bf16x8*)(smem + row * 136 + col);
            *(bf16x8*)(dh + ((size_t)(mt_blk * 128 + row)) * 128 + col) = vv;
        }
        __syncthreads();
        // pass 2: lo
        for (int mt = 0; mt < 4; ++mt)
            for (int nt = 0; nt < 4; ++nt)
                for (int r = 0; r < 4; ++r) {
                    int row = mwb + mt * 16 + q * 4 + r;
                    int col = nwb + nt * 16 + lm;
                    float v = (acc[mt][nt][r] + bias[col]) * scale;
                    bf16 h = (bf16)v;
                    smem[row * 136 + col] = (bf16)(v - (float)h);
                }
        __syncthreads();
        for (int i = 0; i < 8; ++i) {
            int idx = i * 2048 + t * 8;
            int row = idx >> 7, col = idx & 127;
            bf16x8 vv = *(const bf16x8*)(smem + row * 136 + col);
            *(bf16x8*)(dl + ((size_t)(mt_blk * 128 + row)) * 128 + col) = vv;
        }
    } else {
        // Vt: transpose in LDS so stores are contiguous along s
        bf16* vt = ws + VT_OFF;
        size_t b  = mt_blk >> 3;
        int   sb  = (mt_blk & 7) * 128;
        for (int mt = 0; mt < 4; ++mt)
            for (int nt = 0; nt < 4; ++nt)
                for (int r = 0; r < 4; ++r) {
                    int row = mwb + mt * 16 + q * 4 + r;   // s within tile
                    int col = nwb + nt * 16 + lm;          // d
                    float v = acc[mt][nt][r] + bias[col];
                    smem[col * 136 + row] = (bf16)v;
                }
        __syncthreads();
        for (int i = 0; i < 8; ++i) {
            int idx = i * 2048 + t * 8;
            int d = idx >> 7, s8 = idx & 127;
            bf16x8 vv = *(const bf16x8*)(smem + d * 136 + s8);
            *(bf16x8*)(vt + b * 131072 + (size_t)d * 1024 + sb + s8) = vv;
        }
    }
}

// ---------------------------------------------------------------------------
// Kernel 2: fused scores + softmax + probs-store + PV
// grid: 512 blocks (b = bx>>4, mq = bx&15), 512 threads (8 waves)
// QK: wave w owns key cols [128w, 128w+128), all 1024 scores in regs.
// PV: 4 phases; phase g transposes waves 2g,2g+1's probs (keys [256g,256g+256))
//     through LDS into A-layout; every wave then MFMAs its own 16-wide d-tile
//     against those keys -> no cross-wave reduction.
// ---------------------------------------------------------------------------
__global__ __launch_bounds__(512) void attn_fused(const bf16* __restrict__ ws,
                                                  float* __restrict__ out) {
    __shared__ __align__(16) bf16 sm[17408];   // Qh(8704)+Ql(8704); later P(64x264=16896)
    __shared__ float red[8][64];
    __shared__ float rstat[64];
    bf16* Qh = sm;
    bf16* Ql = sm + 8704;
    bf16* P  = sm;

    int bb = blockIdx.x >> 4;
    int mq = blockIdx.x & 15;
    int t  = threadIdx.x;
    int w  = t >> 6;
    int l  = t & 63;
    int lm = l & 15;
    int q  = l >> 4;

    const bf16* qhp = ws + Q_HI + ((size_t)bb * 1024 + mq * 64) * 128;
    const bf16* qlp = ws + Q_LO + ((size_t)bb * 1024 + mq * 64) * 128;
    for (int i = 0; i < 2; ++i) {
        int flat = i * 512 + t;
        int row  = flat >> 4;
        int k8   = (flat & 15) * 8;
        *(u32x4*)(Qh + row * 136 + k8) = *(const u32x4*)(qhp + (size_t)row * 128 + k8);
        *(u32x4*)(Ql + row * 136 + k8) = *(const u32x4*)(qlp + (size_t)row * 128 + k8);
    }
    __syncthreads();

    const bf16* khp = ws + K_HI + (size_t)bb * 131072;
    const bf16* klp = ws + K_LO + (size_t)bb * 131072;

    f32x4 acc[4][8] = {};
    for (int kc = 0; kc < 4; ++kc) {
        bf16x8 ah[4], al[4];
        for (int mt = 0; mt < 4; ++mt) {
            int row = mt * 16 + lm;
            ah[mt] = *(const bf16x8*)(Qh + row * 136 + kc * 32 + q * 8);
            al[mt] = *(const bf16x8*)(Ql + row * 136 + kc * 32 + q * 8);
        }
        // software-pipelined K fragment loads (prefetch next nt)
        size_t kb0 = (size_t)(w * 128 + lm) * 128 + kc * 32 + q * 8;
        bf16x8 pbh = *(const bf16x8*)(khp + kb0);
        bf16x8 pbl = *(const bf16x8*)(klp + kb0);
        for (int nt = 0; nt < 8; ++nt) {
            bf16x8 cbh = pbh, cbl = pbl;
            if (nt < 7) {
                size_t kb = kb0 + (size_t)(nt + 1) * 16 * 128;
                pbh = *(const bf16x8*)(khp + kb);
                pbl = *(const bf16x8*)(klp + kb);
            }
            for (int mt = 0; mt < 4; ++mt) {
                acc[mt][nt] = __builtin_amdgcn_mfma_f32_16x16x32_bf16(ah[mt], cbh, acc[mt][nt], 0, 0, 0);
                acc[mt][nt] = __builtin_amdgcn_mfma_f32_16x16x32_bf16(ah[mt], cbl, acc[mt][nt], 0, 0, 0);
                acc[mt][nt] = __builtin_amdgcn_mfma_f32_16x16x32_bf16(al[mt], cbh, acc[mt][nt], 0, 0, 0);
            }
        }
    }

    // ---- row max
    for (int mt = 0; mt < 4; ++mt)
        for (int r = 0; r < 4; ++r) {
            float m = acc[mt][0][r];
            for (int nt = 1; nt < 8; ++nt) m = fmaxf(m, acc[mt][nt][r]);
            m = fmaxf(m, __shfl_xor(m, 1));
            m = fmaxf(m, __shfl_xor(m, 2));
            m = fmaxf(m, __shfl_xor(m, 4));
            m = fmaxf(m, __shfl_xor(m, 8));
            if (lm == 0) red[w][mt * 16 + q * 4 + r] = m;
        }
    __syncthreads();
    if (t < 64) {
        float m = red[0][t];
        for (int ww = 1; ww < 8; ++ww) m = fmaxf(m, red[ww][t]);
        rstat[t] = m;
    }
    __syncthreads();

    // ---- exp + row sum
    for (int mt = 0; mt < 4; ++mt)
        for (int r = 0; r < 4; ++r) {
            float rm = rstat[mt * 16 + q * 4 + r];
            float s = 0.f;
            for (int nt = 0; nt < 8; ++nt) {
                float e = exp2f((acc[mt][nt][r] - rm) * LOG2E);
                acc[mt][nt][r] = e;
                s += e;
            }
            s += __shfl_xor(s, 1);
            s += __shfl_xor(s, 2);
            s += __shfl_xor(s, 4);
            s += __shfl_xor(s, 8);
            if (lm == 0) red[w][mt * 16 + q * 4 + r] = s;
        }
    __syncthreads();
    if (t < 64) {
        float s = 0.f;
        for (int ww = 0; ww < 8; ++ww) s += red[ww][t];
        rstat[t] = 1.0f / s;
    }
    __syncthreads();

    // ---- normalize in regs + store probs fp32
    float* pout = out + POFF + (size_t)bb * 1048576;
    for (int mt = 0; mt < 4; ++mt)
        for (int r = 0; r < 4; ++r) {
            float inv = rstat[mt * 16 + q * 4 + r];
            int row = mq * 64 + mt * 16 + q * 4 + r;
            for (int nt = 0; nt < 8; ++nt) {
                int col = w * 128 + nt * 16 + lm;
                float p = acc[mt][nt][r] * inv;
                acc[mt][nt][r] = p;
                pout[(size_t)row * 1024 + col] = p;
            }
        }
    __syncthreads();   // Q-region LDS dead; safe to overlay P

    // ---- PV: out-partial per wave over its own d-tile (d = 16w + lm)
    const bf16* vt = ws + VT_OFF + (size_t)bb * 131072;
    f32x4 acco[4] = {};
    for (int g = 0; g < 4; ++g) {
        if ((w >> 1) == g) {
            int colb = (w & 1) * 128;
            for (int mt = 0; mt < 4; ++mt)
                for (int nt = 0; nt < 8; ++nt)
                    for (int r = 0; r < 4; ++r) {
                        int row = mt * 16 + 4 * q + r;
                        int col = colb + nt * 16 + lm;
                        P[row * 264 + col] = (bf16)acc[mt][nt][r];
                    }
        }
        __syncthreads();
        for (int c2 = 0; c2 < 8; ++c2) {
            bf16x8 bv = *(const bf16x8*)(vt + (size_t)(w * 16 + lm) * 1024 + g * 256 + c2 * 32 + q * 8);
            for (int mt = 0; mt < 4; ++mt) {
                bf16x8 ap = *(const bf16x8*)(P + (mt * 16 + lm) * 264 + c2 * 32 + q * 8);
                acco[mt] = __builtin_amdgcn_mfma_f32_16x16x32_bf16(ap, bv, acco[mt], 0, 0, 0);
            }
        }
        __syncthreads();
    }

    // ---- store out: C-layout, d = 16w + lm
    for (int mt = 0; mt < 4; ++mt)
        for (int r = 0; r < 4; ++r) {
            int row = mq * 64 + mt * 16 + 4 * q + r;
            out[((size_t)bb * 1024 + row) * 128 + w * 16 + lm] = acco[mt][r];
        }
}

// ---------------------------------------------------------------------------
extern "C" void kernel_launch(void* const* d_in, const int* in_sizes, int n_in,
                              void* d_out, int out_size, void* d_ws, size_t ws_size,
                              hipStream_t stream) {
    const float* X  = (const float*)d_in[0];
    const float* Wq = (const float*)d_in[1];
    const float* bq = (const float*)d_in[2];
    const float* Wk = (const float*)d_in[3];
    const float* bk = (const float*)d_in[4];
    const float* Wv = (const float*)d_in[5];
    const float* bv = (const float*)d_in[6];
    float* out = (float*)d_out;
    bf16* ws   = (bf16*)d_ws;

    // Xh/Xl live in the (not-yet-needed) probs region of d_out: 2 * 67 MB = 134 MB
    bf16* Xh = (bf16*)(out + POFF);
    bf16* Xl = Xh + 33554432ull;

    prep_x<<<16384, 256, 0, stream>>>(X, Xh, Xl);
    prep_w<<<48, 256, 0, stream>>>(Wq, Wk, Wv, ws);
    qkv_gemm<<<768, 256, 0, stream>>>(Xh, Xl, bq, bk, bv, ws);
    attn_fused<<<512, 512, 0, stream>>>(ws, out);
}

// Round 4
// 429.999 us; speedup vs baseline: 2.3265x; 1.0448x over previous
//
#include <hip/hip_runtime.h>

typedef __bf16 bf16;
typedef __attribute__((ext_vector_type(4))) float   f32x4;
typedef __attribute__((ext_vector_type(4))) __bf16  bf16x4;
typedef __attribute__((ext_vector_type(8))) __bf16  bf16x8;
typedef __attribute__((ext_vector_type(4))) unsigned int u32x4;

#define NB   32
#define SEQ  1024
#define HID  1024
#define HD   128

// ws element offsets (bf16 elements)
#define WT_HI  0ull
#define WT_LO  393216ull
#define Q_HI   786432ull
#define Q_LO   (Q_HI + 4194304ull)
#define K_HI   (Q_HI + 2ull*4194304ull)
#define K_LO   (Q_HI + 3ull*4194304ull)
#define VT_OFF (Q_HI + 4ull*4194304ull)

#define POFF   4194304ull            // probs offset (floats) in d_out
#define SCALE  0.08838834764831845f  // 1/sqrt(128)
#define LOG2E  1.4426950408889634f

#define GLL16(g, l)                                                         \
    __builtin_amdgcn_global_load_lds(                                        \
        (const __attribute__((address_space(1))) void*)(g),                  \
        (__attribute__((address_space(3))) void*)(l), 16, 0, 0)

static __device__ inline void split_f32(float x, bf16& h, bf16& l) {
    h = (bf16)x;
    l = (bf16)(x - (float)h);
}

// ---------------------------------------------------------------------------
// Kernel 0: transpose + hi/lo split of Wq/Wk/Wv -> Wt[z][n(128)][k(1024)]
// grid: 48 blocks = z(3) x ktile(16, 64 rows each); LDS transpose, all
// global reads/writes coalesced 16B.
// ---------------------------------------------------------------------------
__global__ __launch_bounds__(256) void prep_w(const float* __restrict__ Wq,
                                              const float* __restrict__ Wk,
                                              const float* __restrict__ Wv,
                                              bf16* __restrict__ ws) {
    __shared__ bf16 Th[128 * 72];
    __shared__ bf16 Tl[128 * 72];
    int z  = blockIdx.x >> 4;
    int kt = blockIdx.x & 15;
    const float* W = (z == 0) ? Wq : ((z == 1) ? Wk : Wv);
    int t = threadIdx.x;

    for (int i = 0; i < 8; ++i) {
        int idx = (i * 256 + t) * 4;
        int kl  = idx >> 7;          // 0..63
        int n   = idx & 127;
        f32x4 v = *(const f32x4*)(W + (size_t)(kt * 64 + kl) * 128 + n);
        for (int j = 0; j < 4; ++j) {
            bf16 h, lo; split_f32(v[j], h, lo);
            Th[(n + j) * 72 + kl] = h;
            Tl[(n + j) * 72 + kl] = lo;
        }
    }
    __syncthreads();
    for (int i = 0; i < 4; ++i) {
        int idx = (i * 256 + t) * 8;
        int n   = idx >> 6;
        int kl  = idx & 63;
        bf16x8 vh = *(const bf16x8*)(Th + n * 72 + kl);
        bf16x8 vl = *(const bf16x8*)(Tl + n * 72 + kl);
        size_t o = (size_t)z * 131072 + (size_t)n * 1024 + kt * 64 + kl;
        *(bf16x8*)(ws + WT_HI + o) = vh;
        *(bf16x8*)(ws + WT_LO + o) = vl;
    }
}

// ---------------------------------------------------------------------------
// Kernel 1: Q/K/V = X @ W + b  (bf16x2 emulated fp32 via 3 MFMAs)
// X read directly as fp32 via global_load_lds; hi/lo split in VALU at
// fragment-read time. XOR block swizzle on the fp32 tile (row stride =
// exactly 32 banks otherwise).
// grid: 768 blocks (z = bx>>8, mtile = bx&255), 256 threads (4 waves, 2x2)
// ---------------------------------------------------------------------------
__global__ __launch_bounds__(256) void qkv_gemm(const float* __restrict__ X,
                                                const float* __restrict__ bq,
                                                const float* __restrict__ bk,
                                                const float* __restrict__ bv,
                                                bf16* __restrict__ ws) {
    __shared__ __align__(16) char smem_raw[34816];
    float* Xf = (float*)smem_raw;                 // 128x32 fp32, block-swizzled
    bf16*  Bh = (bf16*)(smem_raw + 16384);        // 128x32 bf16
    bf16*  Bl = (bf16*)(smem_raw + 24576);
    bf16*  Ep = (bf16*)smem_raw;                  // epilogue 128x136 bf16

    int z      = blockIdx.x >> 8;
    int mt_blk = blockIdx.x & 255;
    int t  = threadIdx.x;
    int w  = t >> 6;
    int l  = t & 63;
    int lm = l & 15;
    int q  = l >> 4;
    int mwb = (w & 1) * 64;
    int nwb = (w >> 1) * 64;

    const bf16* wth = ws + WT_HI + (size_t)z * 131072;
    const bf16* wtl = ws + WT_LO + (size_t)z * 131072;

    // ---- A staging (fp32): 8 lanes/row, source block = (l&7) ^ (l>>3)
    int srowA = w * 32 + (l >> 3);
    int scolA = ((l & 7) ^ (l >> 3)) * 4;          // floats
    const float* gA = X + (size_t)(mt_blk * 128 + srowA) * 1024 + scolA;
    int lbaseA = (w * 32) * 32;                     // floats, wave-uniform

    // ---- B staging (bf16 hi/lo): 4 lanes/row, XOR swizzle as before
    int srowB = w * 32 + (l >> 2);
    int scolB = ((l & 3) ^ ((l >> 3) & 3)) * 8;
    const bf16* gBh = wth + (size_t)srowB * 1024 + scolB;
    const bf16* gBl = wtl + (size_t)srowB * 1024 + scolB;
    int lbase0 = (w * 32) * 32;
    int lbase1 = (w * 32 + 16) * 32;

    int fcol = (q ^ ((lm >> 1) & 3)) * 8;          // B frag swizzle
    int e7   = lm & 7;                              // A frag swizzle key

    f32x4 acc[4][4] = {};

    for (int kb = 0; kb < 32; ++kb) {
        int go = kb * 32;
        GLL16(gA + go,          Xf + lbaseA);
        GLL16(gA + go + 8192,   Xf + lbaseA + 8 * 32);
        GLL16(gA + go + 16384,  Xf + lbaseA + 16 * 32);
        GLL16(gA + go + 24576,  Xf + lbaseA + 24 * 32);
        GLL16(gBh + go,           Bh + lbase0);
        GLL16(gBh + go + 16384,   Bh + lbase1);
        GLL16(gBl + go,           Bl + lbase0);
        GLL16(gBl + go + 16384,   Bl + lbase1);
        __syncthreads();

        bf16x8 ah[4], al[4], bh[4], bl[4];
        for (int mt = 0; mt < 4; ++mt) {
            int row = mwb + mt * 16 + lm;
            f32x4 v0 = *(const f32x4*)(Xf + row * 32 + ((2 * q)     ^ e7) * 4);
            f32x4 v1 = *(const f32x4*)(Xf + row * 32 + ((2 * q + 1) ^ e7) * 4);
            bf16x8 h, lo;
            for (int j = 0; j < 4; ++j) {
                bf16 hh, ll;
                split_f32(v0[j], hh, ll); h[j] = hh;     lo[j] = ll;
                split_f32(v1[j], hh, ll); h[4 + j] = hh; lo[4 + j] = ll;
            }
            ah[mt] = h; al[mt] = lo;
        }
        for (int nt = 0; nt < 4; ++nt) {
            int row = nwb + nt * 16 + lm;
            bh[nt] = *(const bf16x8*)(Bh + row * 32 + fcol);
            bl[nt] = *(const bf16x8*)(Bl + row * 32 + fcol);
        }
        for (int mt = 0; mt < 4; ++mt)
            for (int nt = 0; nt < 4; ++nt) {
                acc[mt][nt] = __builtin_amdgcn_mfma_f32_16x16x32_bf16(ah[mt], bh[nt], acc[mt][nt], 0, 0, 0);
                acc[mt][nt] = __builtin_amdgcn_mfma_f32_16x16x32_bf16(ah[mt], bl[nt], acc[mt][nt], 0, 0, 0);
                acc[mt][nt] = __builtin_amdgcn_mfma_f32_16x16x32_bf16(al[mt], bh[nt], acc[mt][nt], 0, 0, 0);
            }
        __syncthreads();
    }

    // ---- epilogue via LDS: fully-coalesced 16B stores
    const float* bias = (z == 0) ? bq : ((z == 1) ? bk : bv);
    float scale = (z == 0) ? SCALE : 1.0f;

    if (z < 2) {
        bf16* dh = ws + ((z == 0) ? Q_HI : K_HI);
        bf16* dl = ws + ((z == 0) ? Q_LO : K_LO);
        for (int mt = 0; mt < 4; ++mt)
            for (int nt = 0; nt < 4; ++nt)
                for (int r = 0; r < 4; ++r) {
                    int row = mwb + mt * 16 + q * 4 + r;
                    int col = nwb + nt * 16 + lm;
                    float v = (acc[mt][nt][r] + bias[col]) * scale;
                    Ep[row * 136 + col] = (bf16)v;
                }
        __syncthreads();
        for (int i = 0; i < 8; ++i) {
            int idx = i * 2048 + t * 8;
            int row = idx >> 7, col = idx & 127;
            bf16x8 vv = *(const bf16x8*)(Ep + row * 136 + col);
            *(bf16x8*)(dh + ((size_t)(mt_blk * 128 + row)) * 128 + col) = vv;
        }
        __syncthreads();
        for (int mt = 0; mt < 4; ++mt)
            for (int nt = 0; nt < 4; ++nt)
                for (int r = 0; r < 4; ++r) {
                    int row = mwb + mt * 16 + q * 4 + r;
                    int col = nwb + nt * 16 + lm;
                    float v = (acc[mt][nt][r] + bias[col]) * scale;
                    bf16 h = (bf16)v;
                    Ep[row * 136 + col] = (bf16)(v - (float)h);
                }
        __syncthreads();
        for (int i = 0; i < 8; ++i) {
            int idx = i * 2048 + t * 8;
            int row = idx >> 7, col = idx & 127;
            bf16x8 vv = *(const bf16x8*)(Ep + row * 136 + col);
            *(bf16x8*)(dl + ((size_t)(mt_blk * 128 + row)) * 128 + col) = vv;
        }
    } else {
        bf16* vt = ws + VT_OFF;
        size_t b  = mt_blk >> 3;
        int   sb  = (mt_blk & 7) * 128;
        for (int mt = 0; mt < 4; ++mt)
            for (int nt = 0; nt < 4; ++nt)
                for (int r = 0; r < 4; ++r) {
                    int row = mwb + mt * 16 + q * 4 + r;   // s within tile
                    int col = nwb + nt * 16 + lm;          // d
                    float v = acc[mt][nt][r] + bias[col];
                    Ep[col * 136 + row] = (bf16)v;
                }
        __syncthreads();
        for (int i = 0; i < 8; ++i) {
            int idx = i * 2048 + t * 8;
            int d = idx >> 7, s8 = idx & 127;
            bf16x8 vv = *(const bf16x8*)(Ep + d * 136 + s8);
            *(bf16x8*)(vt + b * 131072 + (size_t)d * 1024 + sb + s8) = vv;
        }
    }
}

// ---------------------------------------------------------------------------
// Kernel 2: fused scores + softmax + probs-store + PV
// grid: 1024 blocks (b = bx>>5, mq = bx&31), 512 threads (8 waves),
// 32 q-rows per block -> 4 blocks/CU.
// QK: wave w owns key cols [128w,128w+128), 2 row-tiles, acc 64 VGPR.
// PV: 2 phases; phase g: waves with w>>2==g scatter probs (keys [512g,+512))
//     into P (stride 516: conflict-free C-layout b16 writes), then all 8
//     waves MFMA their own 16-wide d-tile. No cross-wave reduction.
// ---------------------------------------------------------------------------
__global__ __launch_bounds__(512) void attn_fused(const bf16* __restrict__ ws,
                                                  float* __restrict__ out) {
    __shared__ __align__(16) bf16 sm[16512];   // Qh/Ql (8704 el) then P 32x516
    __shared__ float red[8][32];
    __shared__ float rstat[32];
    bf16* Qh = sm;
    bf16* Ql = sm + 4352;
    bf16* P  = sm;

    int bb = blockIdx.x >> 5;
    int mq = blockIdx.x & 31;
    int t  = threadIdx.x;
    int w  = t >> 6;
    int l  = t & 63;
    int lm = l & 15;
    int q  = l >> 4;

    const bf16* qhp = ws + Q_HI + ((size_t)bb * 1024 + mq * 32) * 128;
    const bf16* qlp = ws + Q_LO + ((size_t)bb * 1024 + mq * 32) * 128;
    {
        int row = t >> 4;
        int k8  = (t & 15) * 8;
        *(u32x4*)(Qh + row * 136 + k8) = *(const u32x4*)(qhp + (size_t)row * 128 + k8);
        *(u32x4*)(Ql + row * 136 + k8) = *(const u32x4*)(qlp + (size_t)row * 128 + k8);
    }
    __syncthreads();

    const bf16* khp = ws + K_HI + (size_t)bb * 131072;
    const bf16* klp = ws + K_LO + (size_t)bb * 131072;

    f32x4 acc[2][8] = {};
    for (int kc = 0; kc < 4; ++kc) {
        bf16x8 ah[2], al[2];
        for (int mt = 0; mt < 2; ++mt) {
            int row = mt * 16 + lm;
            ah[mt] = *(const bf16x8*)(Qh + row * 136 + kc * 32 + q * 8);
            al[mt] = *(const bf16x8*)(Ql + row * 136 + kc * 32 + q * 8);
        }
        size_t kb0 = (size_t)(w * 128 + lm) * 128 + kc * 32 + q * 8;
        bf16x8 pbh = *(const bf16x8*)(khp + kb0);
        bf16x8 pbl = *(const bf16x8*)(klp + kb0);
        for (int nt = 0; nt < 8; ++nt) {
            bf16x8 cbh = pbh, cbl = pbl;
            if (nt < 7) {
                size_t kb = kb0 + (size_t)(nt + 1) * 16 * 128;
                pbh = *(const bf16x8*)(khp + kb);
                pbl = *(const bf16x8*)(klp + kb);
            }
            for (int mt = 0; mt < 2; ++mt) {
                acc[mt][nt] = __builtin_amdgcn_mfma_f32_16x16x32_bf16(ah[mt], cbh, acc[mt][nt], 0, 0, 0);
                acc[mt][nt] = __builtin_amdgcn_mfma_f32_16x16x32_bf16(ah[mt], cbl, acc[mt][nt], 0, 0, 0);
                acc[mt][nt] = __builtin_amdgcn_mfma_f32_16x16x32_bf16(al[mt], cbh, acc[mt][nt], 0, 0, 0);
            }
        }
    }

    // ---- row max
    for (int mt = 0; mt < 2; ++mt)
        for (int r = 0; r < 4; ++r) {
            float m = acc[mt][0][r];
            for (int nt = 1; nt < 8; ++nt) m = fmaxf(m, acc[mt][nt][r]);
            m = fmaxf(m, __shfl_xor(m, 1));
            m = fmaxf(m, __shfl_xor(m, 2));
            m = fmaxf(m, __shfl_xor(m, 4));
            m = fmaxf(m, __shfl_xor(m, 8));
            if (lm == 0) red[w][mt * 16 + q * 4 + r] = m;
        }
    __syncthreads();
    if (t < 32) {
        float m = red[0][t];
        for (int ww = 1; ww < 8; ++ww) m = fmaxf(m, red[ww][t]);
        rstat[t] = m;
    }
    __syncthreads();

    // ---- exp + row sum
    for (int mt = 0; mt < 2; ++mt)
        for (int r = 0; r < 4; ++r) {
            float rm = rstat[mt * 16 + q * 4 + r];
            float s = 0.f;
            for (int nt = 0; nt < 8; ++nt) {
                float e = exp2f((acc[mt][nt][r] - rm) * LOG2E);
                acc[mt][nt][r] = e;
                s += e;
            }
            s += __shfl_xor(s, 1);
            s += __shfl_xor(s, 2);
            s += __shfl_xor(s, 4);
            s += __shfl_xor(s, 8);
            if (lm == 0) red[w][mt * 16 + q * 4 + r] = s;
        }
    __syncthreads();
    if (t < 32) {
        float s = 0.f;
        for (int ww = 0; ww < 8; ++ww) s += red[ww][t];
        rstat[t] = 1.0f / s;
    }
    __syncthreads();

    // ---- normalize in regs + store probs fp32
    float* pout = out + POFF + (size_t)bb * 1048576;
    for (int mt = 0; mt < 2; ++mt)
        for (int r = 0; r < 4; ++r) {
            float inv = rstat[mt * 16 + q * 4 + r];
            int row = mq * 32 + mt * 16 + q * 4 + r;
            for (int nt = 0; nt < 8; ++nt) {
                int col = w * 128 + nt * 16 + lm;
                float p = acc[mt][nt][r] * inv;
                acc[mt][nt][r] = p;
                pout[(size_t)row * 1024 + col] = p;
            }
        }
    __syncthreads();   // Q-region LDS dead; safe to overlay P

    // ---- PV: 2 phases, wave-private d-tile (d = 16w + lm)
    const bf16* vt = ws + VT_OFF + (size_t)bb * 131072;
    f32x4 acco[2] = {};
    for (int g = 0; g < 2; ++g) {
        if ((w >> 2) == g) {
            int colb = (w & 3) * 128;
            for (int mt = 0; mt < 2; ++mt)
                for (int nt = 0; nt < 8; ++nt)
                    for (int r = 0; r < 4; ++r) {
                        int row = mt * 16 + 4 * q + r;
                        int col = colb + nt * 16 + lm;
                        P[row * 516 + col] = (bf16)acc[mt][nt][r];
                    }
        }
        __syncthreads();
        for (int c2 = 0; c2 < 16; ++c2) {
            bf16x8 vb = *(const bf16x8*)(vt + (size_t)(w * 16 + lm) * 1024 + g * 512 + c2 * 32 + q * 8);
            for (int mt = 0; mt < 2; ++mt) {
                bf16x8 ap = *(const bf16x8*)(P + (mt * 16 + lm) * 516 + c2 * 32 + q * 8);
                acco[mt] = __builtin_amdgcn_mfma_f32_16x16x32_bf16(ap, vb, acco[mt], 0, 0, 0);
            }
        }
        __syncthreads();
    }

    // ---- store out: C-layout, d = 16w + lm
    for (int mt = 0; mt < 2; ++mt)
        for (int r = 0; r < 4; ++r) {
            int row = mq * 32 + mt * 16 + 4 * q + r;
            out[((size_t)bb * 1024 + row) * 128 + w * 16 + lm] = acco[mt][r];
        }
}

// ---------------------------------------------------------------------------
extern "C" void kernel_launch(void* const* d_in, const int* in_sizes, int n_in,
                              void* d_out, int out_size, void* d_ws, size_t ws_size,
                              hipStream_t stream) {
    const float* X  = (const float*)d_in[0];
    const float* Wq = (const float*)d_in[1];
    const float* bq = (const float*)d_in[2];
    const float* Wk = (const float*)d_in[3];
    const float* bk = (const float*)d_in[4];
    const float* Wv = (const float*)d_in[5];
    const float* bv = (const float*)d_in[6];
    float* out = (float*)d_out;
    bf16* ws   = (bf16*)d_ws;

    prep_w<<<48, 256, 0, stream>>>(Wq, Wk, Wv, ws);
    qkv_gemm<<<768, 256, 0, stream>>>(X, bq, bk, bv, ws);
    attn_fused<<<1024, 512, 0, stream>>>(ws, out);
}